// Round 1
// baseline (610.104 us; speedup 1.0000x reference)
//
#include <hip/hip_runtime.h>
#include <hip/hip_bf16.h>
#include <cstddef>

#define Bb 4
#define Mm 2048
#define Dd 1024
#define Nn 64
#define Pp 32
#define NP 2048
#define BM 8192

typedef __attribute__((ext_vector_type(4))) float v4f;
typedef __attribute__((ext_vector_type(8))) short v8s;

__device__ inline unsigned short f2b(float f) {
  union { float f; unsigned u; } v; v.f = f;
  unsigned r = v.u + 0x7fff + ((v.u >> 16) & 1);
  return (unsigned short)(r >> 16);
}

__device__ inline void gld16(const void* g, void* l) {
  __builtin_amdgcn_global_load_lds(
      (const __attribute__((address_space(1))) unsigned*)g,
      (__attribute__((address_space(3))) unsigned*)l, 16, 0, 0);
}

// ---------------------------------------------------------------------------
// k_xprep: one pass over x. Writes xb (bf16, [b][m][d]) and xT (bf16, [b][d][m]).
// ---------------------------------------------------------------------------
__global__ __launch_bounds__(256) void k_xprep(const float* __restrict__ x,
                                               unsigned short* __restrict__ xb,
                                               unsigned short* __restrict__ xT) {
  __shared__ unsigned short t[32][33];
  const int b = blockIdx.z;
  const int r0 = blockIdx.y * 32;   // m
  const int c0 = blockIdx.x * 32;   // d
  const float* ib = x + (size_t)b * Mm * Dd;
  const int tr = threadIdx.x >> 3;
  const int tc = (threadIdx.x & 7) * 4;
  float4 v = *(const float4*)&ib[(size_t)(r0 + tr) * Dd + c0 + tc];
  ushort4 s;
  s.x = f2b(v.x); s.y = f2b(v.y); s.z = f2b(v.z); s.w = f2b(v.w);
  *(ushort4*)&xb[(size_t)b * Mm * Dd + (size_t)(r0 + tr) * Dd + c0 + tc] = s;
  t[tr][tc + 0] = s.x; t[tr][tc + 1] = s.y;
  t[tr][tc + 2] = s.z; t[tr][tc + 3] = s.w;
  __syncthreads();
  ushort4 o;
  o.x = t[tc + 0][tr]; o.y = t[tc + 1][tr];
  o.z = t[tc + 2][tr]; o.w = t[tc + 3][tr];
  *(ushort4*)&xT[(size_t)b * Dd * Mm + (size_t)(c0 + tr) * Mm + r0 + tc] = o;
}

// ---------------------------------------------------------------------------
// tiled transpose fp32 -> bf16 : in [R][C] -> out [C][R] (for phi)
// ---------------------------------------------------------------------------
__global__ __launch_bounds__(256) void k_tr_f2b(const float* __restrict__ in,
                                                unsigned short* __restrict__ out,
                                                int R, int C) {
  __shared__ unsigned short t[32][33];
  const int r0 = blockIdx.y * 32, c0 = blockIdx.x * 32;
  const int tr = threadIdx.x >> 3;
  const int tc = (threadIdx.x & 7) * 4;
  float4 v = *(const float4*)&in[(size_t)(r0 + tr) * C + c0 + tc];
  t[tr][tc + 0] = f2b(v.x); t[tr][tc + 1] = f2b(v.y);
  t[tr][tc + 2] = f2b(v.z); t[tr][tc + 3] = f2b(v.w);
  __syncthreads();
  ushort4 o;
  o.x = t[tc + 0][tr]; o.y = t[tc + 1][tr];
  o.z = t[tc + 2][tr]; o.w = t[tc + 3][tr];
  *(ushort4*)&out[(size_t)(c0 + tr) * R + r0 + tc] = o;
}

// bf16 -> bf16 batched transpose
__global__ __launch_bounds__(256) void k_tr_b2b(const unsigned short* __restrict__ in, size_t sin_,
                                                unsigned short* __restrict__ out, size_t sout,
                                                int R, int C) {
  __shared__ unsigned short t[32][33];
  const int r0 = blockIdx.y * 32, c0 = blockIdx.x * 32;
  const unsigned short* ib = in + (size_t)blockIdx.z * sin_;
  unsigned short* ob = out + (size_t)blockIdx.z * sout;
  const int tr = threadIdx.x >> 3;
  const int tc = (threadIdx.x & 7) * 4;
  ushort4 v = *(const ushort4*)&ib[(size_t)(r0 + tr) * C + c0 + tc];
  t[tr][tc + 0] = v.x; t[tr][tc + 1] = v.y;
  t[tr][tc + 2] = v.z; t[tr][tc + 3] = v.w;
  __syncthreads();
  ushort4 o;
  o.x = t[tc + 0][tr]; o.y = t[tc + 1][tr];
  o.z = t[tc + 2][tr]; o.w = t[tc + 3][tr];
  *(ushort4*)&ob[(size_t)(c0 + tr) * R + r0 + tc] = o;
}

// ---------------------------------------------------------------------------
// bf16 MFMA GEMM, BK=64 dual-buffer: C[M,N] = A[M,K] @ B^T[N,K]
// One barrier pair per 64 K-elements; 32 MFMA between barriers.
// ---------------------------------------------------------------------------
template <int OUT_BF16>
__global__ __launch_bounds__(256) void k_gemm(const unsigned short* __restrict__ A, size_t sA,
                                              const unsigned short* __restrict__ B, size_t sB,
                                              void* __restrict__ C, size_t sC,
                                              int M, int N, int K) {
  __shared__ unsigned short As[2][128][32];
  __shared__ unsigned short Bs[2][128][32];
  const int tid = threadIdx.x;
  const int wv = tid >> 6, ln = tid & 63;
  const int wm = wv & 1, wn = wv >> 1;
  const int row0 = blockIdx.y * 128, col0 = blockIdx.x * 128;
  const unsigned short* Ab = A + (size_t)blockIdx.z * sA + (size_t)row0 * K;
  const unsigned short* Bbp = B + (size_t)blockIdx.z * sB + (size_t)col0 * K;
  const int sr = ln >> 2;
  const int sc = (ln & 3) * 8;
  const int fr = ln & 15, fc = (ln >> 4) * 8;
  v4f acc[4][4];
#pragma unroll
  for (int i = 0; i < 4; ++i)
#pragma unroll
    for (int j = 0; j < 4; ++j) { v4f z = {0.f, 0.f, 0.f, 0.f}; acc[i][j] = z; }

  for (int kt = 0; kt < K; kt += 64) {
    __syncthreads();
    const size_t ga1 = (size_t)(32 * wv + sr) * K + kt + sc;
    const size_t ga2 = (size_t)(32 * wv + 16 + sr) * K + kt + sc;
    gld16(Ab + ga1,       &As[0][32 * wv][0]);
    gld16(Ab + ga2,       &As[0][32 * wv + 16][0]);
    gld16(Ab + ga1 + 32,  &As[1][32 * wv][0]);
    gld16(Ab + ga2 + 32,  &As[1][32 * wv + 16][0]);
    gld16(Bbp + ga1,      &Bs[0][32 * wv][0]);
    gld16(Bbp + ga2,      &Bs[0][32 * wv + 16][0]);
    gld16(Bbp + ga1 + 32, &Bs[1][32 * wv][0]);
    gld16(Bbp + ga2 + 32, &Bs[1][32 * wv + 16][0]);
    __syncthreads();
#pragma unroll
    for (int ks = 0; ks < 2; ++ks) {
      v8s a[4], b[4];
#pragma unroll
      for (int i = 0; i < 4; ++i) a[i] = *(const v8s*)&As[ks][64 * wm + 16 * i + fr][fc];
#pragma unroll
      for (int j = 0; j < 4; ++j) b[j] = *(const v8s*)&Bs[ks][64 * wn + 16 * j + fr][fc];
#pragma unroll
      for (int i = 0; i < 4; ++i)
#pragma unroll
        for (int j = 0; j < 4; ++j)
          acc[i][j] = __builtin_amdgcn_mfma_f32_16x16x32_bf16(a[i], b[j], acc[i][j], 0, 0, 0);
    }
  }
  const int er = (ln >> 4) * 4, ec = ln & 15;
#pragma unroll
  for (int i = 0; i < 4; ++i)
#pragma unroll
    for (int j = 0; j < 4; ++j) {
      int r = row0 + 64 * wm + 16 * i + er;
      int c = col0 + 64 * wn + 16 * j + ec;
      if (OUT_BF16) {
        unsigned short* Cp = (unsigned short*)C + (size_t)blockIdx.z * sC + (size_t)r * N + c;
#pragma unroll
        for (int q = 0; q < 4; ++q) Cp[(size_t)q * N] = f2b(acc[i][j][q]);
      } else {
        float* Cp = (float*)C + (size_t)blockIdx.z * sC + (size_t)r * N + c;
#pragma unroll
        for (int q = 0; q < 4; ++q) Cp[(size_t)q * N] = acc[i][j][q];
      }
    }
}

// ---------------------------------------------------------------------------
// softmaxes (shuffle-reduce). One block per m.
// Pass 2 of the combine softmax now caches exp() into sh (saves a third
// full exp pass over B*NP elements per m).
// ---------------------------------------------------------------------------
__global__ __launch_bounds__(256) void k_softmax(const float* __restrict__ logits,
                                                 unsigned short* __restrict__ dispatch,
                                                 unsigned short* __restrict__ combine) {
  __shared__ float sh[Bb][NP];
  __shared__ float redm[Bb][4];
  __shared__ float reds[Bb][4];
  const int m = blockIdx.x;
  const int tid = threadIdx.x;
  const int wv = tid >> 6, ln = tid & 63;
#pragma unroll
  for (int b = 0; b < Bb; ++b) {
    const float4* src = (const float4*)(logits + ((size_t)b * Mm + m) * NP);
#pragma unroll
    for (int it = 0; it < 2; ++it) ((float4*)sh[b])[tid + it * 256] = src[tid + it * 256];
  }
  __syncthreads();
#pragma unroll
  for (int it = 0; it < 8; ++it) {
    int np = tid + it * 256;
    float v0 = sh[0][np], v1 = sh[1][np], v2 = sh[2][np], v3 = sh[3][np];
    float mx = fmaxf(fmaxf(v0, v1), fmaxf(v2, v3));
    float e0 = __expf(v0 - mx), e1 = __expf(v1 - mx);
    float e2 = __expf(v2 - mx), e3 = __expf(v3 - mx);
    float inv = 1.0f / (e0 + e1 + e2 + e3);
    dispatch[((size_t)0 * Mm + m) * NP + np] = f2b(e0 * inv);
    dispatch[((size_t)1 * Mm + m) * NP + np] = f2b(e1 * inv);
    dispatch[((size_t)2 * Mm + m) * NP + np] = f2b(e2 * inv);
    dispatch[((size_t)3 * Mm + m) * NP + np] = f2b(e3 * inv);
  }
#pragma unroll
  for (int b = 0; b < Bb; ++b) {
    float lmax = -3.0e38f;
#pragma unroll
    for (int it = 0; it < 8; ++it) lmax = fmaxf(lmax, sh[b][tid + it * 256]);
#pragma unroll
    for (int o = 32; o > 0; o >>= 1) lmax = fmaxf(lmax, __shfl_xor(lmax, o, 64));
    if (ln == 0) redm[b][wv] = lmax;
    __syncthreads();
    float mx = fmaxf(fmaxf(redm[b][0], redm[b][1]), fmaxf(redm[b][2], redm[b][3]));
    float lsum = 0.0f;
#pragma unroll
    for (int it = 0; it < 8; ++it) {
      int np = tid + it * 256;
      float e = __expf(sh[b][np] - mx);
      sh[b][np] = e;              // cache: each thread overwrites only its own slots
      lsum += e;
    }
#pragma unroll
    for (int o = 32; o > 0; o >>= 1) lsum += __shfl_xor(lsum, o, 64);
    if (ln == 0) reds[b][wv] = lsum;
    __syncthreads();
    float inv = 1.0f / (reds[b][0] + reds[b][1] + reds[b][2] + reds[b][3]);
#pragma unroll
    for (int it = 0; it < 8; ++it) {
      int np = tid + it * 256;
      combine[((size_t)b * Mm + m) * NP + np] = f2b(sh[b][np] * inv);
    }
  }
}

// ---------------------------------------------------------------------------
// k_y: per expert n, BK=64 dual-buffer. A (slots) via gld16; W fp32 staged
// through VALU cvt into padded LDS.
//
// Staging thread->(e,k) remap (this round): old mapping k=(idx>>5)*2,
// eseg=(idx&31)*4 made lanes 0-31 of a wave write rows 4i at bank
// (16*i mod 32)+c -> 2 banks / 32 lanes = 16-way conflict on every
// ds_write_b32 (5.7x, m136), and staging is the 2-phase critical path.
// New mapping: kp=(l>>2)&15, e4=(l&3)+4*(idx>>6): bank =
// kp + 16*(l&1) + 20*j -> every bank hit exactly 2x = conflict-free.
// Global W reads remain fully coalesced (4 lanes x float4 = aligned 64B
// per W row).
// ---------------------------------------------------------------------------
__global__ __launch_bounds__(256) void k_y_mfma(const unsigned short* __restrict__ slots,
                                                const float* __restrict__ W,
                                                const float* __restrict__ bias,
                                                unsigned short* __restrict__ y) {
  __shared__ unsigned short As[2][128][32];
  __shared__ unsigned short Bs[2][128][40];
  const int n = blockIdx.z;
  const int col0 = blockIdx.x * 128;
  const int tid = threadIdx.x;
  const int wv = tid >> 6, ln = tid & 63;
  const int wm = wv & 1, wn = wv >> 1;
  const int sr = ln >> 2, sc = (ln & 3) * 8;
  const int fr = ln & 15, fc = (ln >> 4) * 8;
  const float* Wn = W + (size_t)n * Dd * Dd;
  v4f acc[4][4];
#pragma unroll
  for (int i = 0; i < 4; ++i)
#pragma unroll
    for (int j = 0; j < 4; ++j) { v4f z = {0.f, 0.f, 0.f, 0.f}; acc[i][j] = z; }

  for (int kt = 0; kt < Dd; kt += 64) {
    __syncthreads();
    {
      int r1 = 32 * wv + sr;
      int r2 = r1 + 16;
      size_t g1 = ((size_t)(r1 >> 5) * NP + n * Pp + (r1 & 31)) * Dd + kt + sc;
      size_t g2 = ((size_t)(r2 >> 5) * NP + n * Pp + (r2 & 31)) * Dd + kt + sc;
      gld16(slots + g1,      &As[0][32 * wv][0]);
      gld16(slots + g2,      &As[0][32 * wv + 16][0]);
      gld16(slots + g1 + 32, &As[1][32 * wv][0]);
      gld16(slots + g2 + 32, &As[1][32 * wv + 16][0]);
    }
#pragma unroll
    for (int buf = 0; buf < 2; ++buf) {
#pragma unroll
      for (int it = 0; it < 2; ++it) {
        int idx = tid + it * 256;
        int k = ((idx >> 2) & 15) * 2;                    // 16 k-pairs per wave
        int eseg = ((idx & 3) + ((idx >> 6) << 2)) * 4;   // 4-lane e-groups (64B lines)
        const float* wp = &Wn[(size_t)(kt + buf * 32 + k) * Dd + col0 + eseg];
        float4 r0 = *(const float4*)wp;
        float4 r1 = *(const float4*)(wp + Dd);
        *(__hip_bfloat162*)&Bs[buf][eseg + 0][k] = __float22bfloat162_rn(float2{r0.x, r1.x});
        *(__hip_bfloat162*)&Bs[buf][eseg + 1][k] = __float22bfloat162_rn(float2{r0.y, r1.y});
        *(__hip_bfloat162*)&Bs[buf][eseg + 2][k] = __float22bfloat162_rn(float2{r0.z, r1.z});
        *(__hip_bfloat162*)&Bs[buf][eseg + 3][k] = __float22bfloat162_rn(float2{r0.w, r1.w});
      }
    }
    __syncthreads();
#pragma unroll
    for (int ks = 0; ks < 2; ++ks) {
      v8s a[4], b[4];
#pragma unroll
      for (int i = 0; i < 4; ++i) a[i] = *(const v8s*)&As[ks][64 * wm + 16 * i + fr][fc];
#pragma unroll
      for (int j = 0; j < 4; ++j) b[j] = *(const v8s*)&Bs[ks][64 * wn + 16 * j + fr][fc];
#pragma unroll
      for (int i = 0; i < 4; ++i)
#pragma unroll
        for (int j = 0; j < 4; ++j)
          acc[i][j] = __builtin_amdgcn_mfma_f32_16x16x32_bf16(a[i], b[j], acc[i][j], 0, 0, 0);
    }
  }
  const int er = (ln >> 4) * 4, ec = ln & 15;
  float bv[4];
#pragma unroll
  for (int j = 0; j < 4; ++j) bv[j] = bias[(size_t)n * Dd + col0 + 64 * wn + 16 * j + ec];
#pragma unroll
  for (int i = 0; i < 4; ++i)
#pragma unroll
    for (int j = 0; j < 4; ++j) {
      int c = col0 + 64 * wn + 16 * j + ec;
#pragma unroll
      for (int q = 0; q < 4; ++q) {
        int r = 64 * wm + 16 * i + er + q;
        size_t row = (size_t)(r >> 5) * NP + n * Pp + (r & 31);
        y[row * Dd + c] = f2b(acc[i][j][q] + bv[j]);
      }
    }
}

// ---------------------------------------------------------------------------
extern "C" void kernel_launch(void* const* d_in, const int* in_sizes, int n_in,
                              void* d_out, int out_size, void* d_ws, size_t ws_size,
                              hipStream_t stream) {
  const float* x    = (const float*)d_in[0];
  const float* phi  = (const float*)d_in[1];
  const float* W    = (const float*)d_in[2];
  const float* bias = (const float*)d_in[3];
  float* out = (float*)d_out;
  char* ws = (char*)d_ws;

  float*          logits = (float*)(ws);                            // 67.1 MB
  unsigned short* disp_b = (unsigned short*)(ws + 67108864);        // 33.5 MB
  unsigned short* comb_b = (unsigned short*)(ws + 100663296);       // 33.5 MB
  unsigned short* dispT  = (unsigned short*)(ws + 134217728);       // 33.5 MB
  unsigned short* xb     = (unsigned short*)(ws + 167772160);       // 16.8 MB
  unsigned short* xT     = (unsigned short*)(ws + 184549376);       // 16.8 MB
  unsigned short* phiT   = (unsigned short*)(ws + 201326592);       //  4.2 MB
  unsigned short* slots  = (unsigned short*)(ws + 209715200);       // 16.8 MB
  unsigned short* y_b    = (unsigned short*)(ws + 226492416);       // 16.8 MB
  unsigned short* yT     = (unsigned short*)(ws + 243269632);       // 16.8 MB

  k_xprep<<<dim3(32, 64, Bb), 256, 0, stream>>>(x, xb, xT);
  k_tr_f2b<<<dim3(64, 32, 1), 256, 0, stream>>>(phi, phiT, Dd, NP);
  k_gemm<0><<<dim3(16, 64, 1), 256, 0, stream>>>(xb, 0, phiT, 0, logits, 0, BM, NP, Dd);
  k_softmax<<<Mm, 256, 0, stream>>>(logits, disp_b, comb_b);
  k_tr_b2b<<<dim3(64, 64, Bb), 256, 0, stream>>>(disp_b, (size_t)Mm * NP, dispT, (size_t)NP * Mm, Mm, NP);
  k_gemm<1><<<dim3(8, 16, Bb), 256, 0, stream>>>(dispT, (size_t)NP * Mm, xT, (size_t)Dd * Mm,
                                                 slots, (size_t)NP * Dd, NP, Dd, Mm);
  k_y_mfma<<<dim3(8, 1, Nn), 256, 0, stream>>>(slots, W, bias, y_b);
  k_tr_b2b<<<dim3(32, 64, Bb), 256, 0, stream>>>(y_b, (size_t)NP * Dd, yT, (size_t)Dd * NP, NP, Dd);
  k_gemm<0><<<dim3(8, 16, Bb), 256, 0, stream>>>(comb_b, (size_t)Mm * NP, yT, (size_t)Dd * NP,
                                                 out, (size_t)Mm * Dd, Mm, Dd, NP);
}